// Round 6
// baseline (672.044 us; speedup 1.0000x reference)
//
#include <hip/hip_runtime.h>
#include <math.h>

#define NN 256
#define NPIX 65536
#define NFIELD 81
#define NF2 41
#define FPAD 48              // psit row stride (floats), 12 float4s
#define NPAIR_PAD 1024
#define KSPLIT2 512
#define KPB2 (NPIX / KSPLIT2)    // 128 k per block
#define KCH2 32
#define NCH2 (KPB2 / KCH2)       // 4 chunks
#define PBLK 256                 // pairs per block (4 waves x 64)
#define EPSF 1e-8f

// ---------------- FFT helpers (256-point, LDS-resident) ----------------
// DIF: natural order in -> bit-reversed out.  DIT: bit-reversed in -> natural out.
// Composition DIF(inverse) -> pointwise -> DIT(forward) needs no explicit reversal.

__device__ inline void make_tw(float* twc, float* tws, int tid, int nthr) {
    for (int i = tid; i < 128; i += nthr) {
        float ang = (float)i * (6.283185307179586f / 256.0f);
        twc[i] = cosf(ang);
        tws[i] = sinf(ang);
    }
}

template<int T>
__device__ inline void dif_fft(float2* row, const float* twc, const float* tws,
                               float sgn, int lane) {
    #pragma unroll
    for (int s = 0; s < 8; ++s) {
        int half = 128 >> s;
        __syncthreads();
        #pragma unroll
        for (int bi = 0; bi < 128 / T; ++bi) {
            int b = lane + bi * T;
            int t = b & (half - 1);
            int blk = b >> (7 - s);
            int p0 = (blk << (8 - s)) + t;
            float2 u = row[p0];
            float2 v = row[p0 + half];
            row[p0] = make_float2(u.x + v.x, u.y + v.y);
            float dx = u.x - v.x, dy = u.y - v.y;
            int w = t << s;
            float c = twc[w], si = sgn * tws[w];
            row[p0 + half] = make_float2(dx * c - dy * si, dx * si + dy * c);
        }
    }
    __syncthreads();
}

template<int T>
__device__ inline void dit_fft(float2* row, const float* twc, const float* tws,
                               float sgn, int lane) {
    #pragma unroll
    for (int s = 0; s < 8; ++s) {
        int half = 1 << s;
        __syncthreads();
        #pragma unroll
        for (int bi = 0; bi < 128 / T; ++bi) {
            int b = lane + bi * T;
            int t = b & (half - 1);
            int blk = b >> s;
            int p0 = (blk << (s + 1)) + t;
            int w = t << (7 - s);
            float c = twc[w], si = sgn * tws[w];
            float2 v = row[p0 + half];
            float vx = v.x * c - v.y * si;
            float vy = v.x * si + v.y * c;
            float2 u = row[p0];
            row[p0] = make_float2(u.x + vx, u.y + vy);
            row[p0 + half] = make_float2(u.x - vx, u.y - vy);
        }
    }
    __syncthreads();
}

// ---------------- K0: psit[pix][f] = r^2 + i^2 (transposed, zero-padded) ----------------
__global__ void k0_psit(const float* __restrict__ r, const float* __restrict__ im,
                        float* __restrict__ psit) {
    __shared__ float tile[64 * FPAD];
    int tid = threadIdx.x;
    int base = blockIdx.x * 64;   // pixel base
    for (int idx = tid; idx < NF2 * 64; idx += 256) {
        int f = idx >> 6, px = idx & 63;
        size_t g = (size_t)f * NPIX + base + px;
        float a = r[g], b = im[g];
        tile[px * FPAD + f] = a * a + b * b;
    }
    for (int idx = tid; idx < 64 * (FPAD - NF2); idx += 256) {
        int px = idx / (FPAD - NF2), f = NF2 + idx % (FPAD - NF2);
        tile[px * FPAD + f] = 0.f;
    }
    __syncthreads();
    for (int idx = tid; idx < 64 * FPAD; idx += 256)
        psit[(size_t)base * FPAD + idx] = tile[idx];
}

// ---------------- K1: rows -> product with psi, inverse DIF over x ----------------
__global__ void k1_rowifft(const float* __restrict__ xhat,
                           const float* __restrict__ psiR,
                           const float* __restrict__ psiI,
                           float2* __restrict__ P) {
    __shared__ float2 buf[4][257];
    __shared__ float twc[128], tws[128];
    int tid = threadIdx.x;
    make_tw(twc, tws, tid, 256);
    int fi = tid >> 6, lane = tid & 63;
    int f = blockIdx.y;
    int y = blockIdx.x * 4 + fi;
    const float inv = 1.0f / 256.0f;
    size_t rb = (size_t)f * NPIX + (size_t)y * NN;
    for (int j = lane; j < NN; j += 64) {
        float xr = xhat[(y * NN + j) * 2 + 0];
        float xi = xhat[(y * NN + j) * 2 + 1];
        float pr = psiR[rb + j], pi = psiI[rb + j];
        buf[fi][j] = make_float2((xr * pr - xi * pi) * inv, (xr * pi + xi * pr) * inv);
    }
    dif_fft<64>(&buf[fi][0], twc, tws, +1.0f, lane);
    for (int j = lane; j < NN; j += 64) P[rb + j] = buf[fi][j];
}

// ---------------- K2: per column: inverse DIF over y, modulus, forward DIT over y ----------------
__global__ void k2_colpass(float2* __restrict__ P) {
    __shared__ float2 buf[16][257];
    __shared__ float twc[128], tws[128];
    int tid = threadIdx.x;      // 256 threads: 16 columns x 16 threads
    make_tw(twc, tws, tid, 256);
    int c = tid & 15, tl = tid >> 4;
    int f = blockIdx.y;
    int xb = blockIdx.x * 16;
    size_t fb = (size_t)f * NPIX;
    #pragma unroll
    for (int i = 0; i < 16; ++i) {
        int y = tl + i * 16;
        buf[c][y] = P[fb + (size_t)y * NN + xb + c];
    }
    dif_fft<16>(&buf[c][0], twc, tws, +1.0f, tl);
    const float inv = 1.0f / 256.0f;
    #pragma unroll
    for (int i = 0; i < 16; ++i) {
        int p = tl + i * 16;
        float2 v = buf[c][p];
        float vx = v.x * inv, vy = v.y * inv;
        buf[c][p] = make_float2(sqrtf(vx * vx + vy * vy + EPSF), 0.0f);
    }
    dit_fft<16>(&buf[c][0], twc, tws, -1.0f, tl);
    #pragma unroll
    for (int i = 0; i < 16; ++i) {
        int y = tl + i * 16;
        P[fb + (size_t)y * NN + xb + c] = buf[c][y];
    }
}

// ---------------- K3: rows -> forward DIT over x (consumes bitrev-x) ----------------
__global__ void k3_rowfft(float2* __restrict__ P) {
    __shared__ float2 buf[4][257];
    __shared__ float twc[128], tws[128];
    int tid = threadIdx.x;
    make_tw(twc, tws, tid, 256);
    int fi = tid >> 6, lane = tid & 63;
    int f = blockIdx.y;
    int y = blockIdx.x * 4 + fi;
    size_t rb = (size_t)f * NPIX + (size_t)y * NN;
    for (int j = lane; j < NN; j += 64) buf[fi][j] = P[rb + j];
    dit_fft<64>(&buf[fi][0], twc, tws, -1.0f, lane);
    for (int j = lane; j < NN; j += 64) P[rb + j] = buf[fi][j];
}

// ---------------- pair enumeration, SORTED by f-start group ----------------
// group g covers pairs [G[g], G[g+1]) with fstart = 8*g.
// Within group g: M pairs j=2g (36, tri a<=b), M pairs j=2g+1 (36),
//                 N pairs l=2g (8*l, skipped for g=0), N pairs l=2g+1 (8*l),
//                 then (g==4 only) A pairs (80).  s==800: s0.  801..1023: pad.
__device__ __host__ inline int fsj(int j) { int t = j >> 1; return (t > 4 ? 4 : t) * 8; }

__device__ inline int group_of(int s) {
    return (s < 80) ? 0 : (s < 192) ? 1 : (s < 336) ? 2 : (s < 512) ? 3 : 4;
}

__device__ inline void pair_sorted(int s, int& u, int& v) {
    if (s >= 800) { u = 80; v = 80; return; }   // s0 and pad
    const int Gs[5] = {0, 80, 192, 336, 512};
    int g = group_of(s);
    int r = s - Gs[g];
    if (r < 72) {                       // M section
        int j = 2 * g + (r >= 36);
        int rr = (r >= 36) ? r - 36 : r;
        int a = 0;
        while (rr >= 8 - a) { rr -= 8 - a; ++a; }
        int b = a + rr;
        u = a * 10 + j; v = b * 10 + j;
        return;
    }
    int r2 = r - 72;                    // N section
    int l0 = 2 * g;
    int c0 = (l0 >= 1) ? 8 * l0 : 0;
    if (r2 < c0) { int i = r2 / l0, j = r2 % l0; u = i * 10 + j; v = i * 10 + l0; return; }
    r2 -= c0;
    int l1 = 2 * g + 1;
    if (r2 < 8 * l1) { int i = r2 / l1, j = r2 % l1; u = i * 10 + j; v = i * 10 + l1; return; }
    r2 -= 8 * l1;                       // A section (g==4 only): r2 = i*10+j
    u = r2; v = 80;
}

// inverse maps (for c2): sorted index of each pair type
__device__ inline int pM(int a, int b, int j) {
    const int Gt[5] = {0, 80, 192, 336, 512};
    return Gt[j >> 1] + (j & 1) * 36 + a * 8 - a * (a - 1) / 2 + (b - a);
}
__device__ inline int pN(int i, int j, int l) {
    const int Gt[5] = {0, 80, 192, 336, 512};
    return Gt[l >> 1] + 72 + ((l & 1) ? 8 * (l - 1) : 0) + i * l + j;
}
// A pairs: 720 + i*10 + j ; s0: 800  (same as sorted layout)

// ---------------- C1: lane-per-pair, psi via scalar loads, Pt gather via LDS ----------------
__global__ void __launch_bounds__(256) c1_contract(const float2* __restrict__ P,
                                                   const float* __restrict__ psit,
                                                   float* __restrict__ Mout) {
    __shared__ float2 ptl[KCH2 * 88];    // [k][field], rows 704B
    int tid = threadIdx.x;
    int split = blockIdx.x, btile = blockIdx.y;
    int p = btile * PBLK + tid;          // this lane's pair
    int u, v;
    pair_sorted(p, u, v);
    int wbase = btile * PBLK + (tid & ~63);
    int qs = __builtin_amdgcn_readfirstlane(2 * group_of(wbase));  // first f-quad
    float ar[11][4], ai[11][4];
    #pragma unroll
    for (int q = 0; q < 11; ++q)
        #pragma unroll
        for (int fi = 0; fi < 4; ++fi) { ar[q][fi] = 0.f; ai[q][fi] = 0.f; }

    for (int ch = 0; ch < NCH2; ++ch) {
        int kbase = split * KPB2 + ch * KCH2;
        __syncthreads();
        for (int idx = tid; idx < NFIELD * KCH2; idx += 256) {
            int f = idx >> 5, kk = idx & 31;
            ptl[kk * 88 + f] = P[(size_t)f * NPIX + kbase + kk];
        }
        __syncthreads();
        for (int kk = 0; kk < KCH2; ++kk) {
            float2 A = ptl[kk * 88 + u];
            float2 B = ptl[kk * 88 + v];
            float cre = A.x * B.x + A.y * B.y;
            float cim = A.y * B.x - A.x * B.y;
            const float4* qr = (const float4*)(psit + (size_t)(kbase + kk) * FPAD);
            #pragma unroll
            for (int q = 0; q < 11; ++q) {
                if (q >= qs) {
                    float4 pq = qr[q];
                    ar[q][0] += pq.x * cre; ai[q][0] += pq.x * cim;
                    ar[q][1] += pq.y * cre; ai[q][1] += pq.y * cim;
                    ar[q][2] += pq.z * cre; ai[q][2] += pq.z * cim;
                    ar[q][3] += pq.w * cre; ai[q][3] += pq.w * cim;
                }
            }
        }
    }
    #pragma unroll
    for (int q = 0; q < 11; ++q) {
        if (q >= qs) {
            #pragma unroll
            for (int fi = 0; fi < 4; ++fi) {
                int f = q * 4 + fi;
                atomicAdd(&Mout[((size_t)f * NPAIR_PAD + p) * 2 + 0], ar[q][fi]);
                atomicAdd(&Mout[((size_t)f * NPAIR_PAD + p) * 2 + 1], ai[q][fi]);
            }
        }
    }
}

// ---------------- C2: magnitude + assembly in reference output order ----------------
__device__ inline int seglen_d(int j, int i) {
    int s = (NF2 - fsj(j)) * (8 - i) + 9;
    for (int l = j + 1; l < 10; ++l) s += NF2 - fsj(l);
    return s;
}

__device__ inline float magof(const float* Mout, int f, int p) {
    const float nrm = 1.0f / 65536.0f;
    float re = Mout[((size_t)f * NPAIR_PAD + p) * 2 + 0] * nrm;
    float im = Mout[((size_t)f * NPAIR_PAD + p) * 2 + 1] * nrm;
    return sqrtf(re * re + im * im + EPSF);
}

__global__ void c2_assemble(const float* __restrict__ Mout, float* __restrict__ out) {
    int bid = blockIdx.x, tid = threadIdx.x;
    if (bid == 0) {
        if (tid == 0) out[0] = magof(Mout, 40, 800);   // s0
        return;
    }
    int idx = bid - 1;
    int j = idx / 8, i = idx % 8;
    int base = 1;
    for (int q = 0; q < idx; ++q) base += seglen_d(q / 8, q % 8);
    int fs = fsj(j);
    int d = 8 - i;
    int len1 = (NF2 - fs) * d;
    int total = seglen_d(j, i);
    for (int e = tid; e < total; e += 256) {
        int f, p;
        if (e < len1) {
            f = fs + e / d;
            int b = i + e % d;
            p = pM(i, b, j);
        } else {
            int e2 = e - len1;
            bool found = false;
            f = 0; p = 0;
            for (int l = j + 1; l < 10; ++l) {
                int ll = NF2 - fsj(l);
                if (e2 < ll) {
                    f = fsj(l) + e2;
                    p = pN(i, j, l);
                    found = true;
                    break;
                }
                e2 -= ll;
            }
            if (!found) { f = 32 + e2; p = 720 + i * 10 + j; }
        }
        out[base + e] = magof(Mout, f, p);
    }
}

// ---------------- launch ----------------
extern "C" void kernel_launch(void* const* d_in, const int* in_sizes, int n_in,
                              void* d_out, int out_size, void* d_ws, size_t ws_size,
                              hipStream_t stream) {
    const float* xhat  = (const float*)d_in[0];
    const float* psiR  = (const float*)d_in[1];
    const float* psiI  = (const float*)d_in[2];
    const float* p2R   = (const float*)d_in[3];
    const float* p2I   = (const float*)d_in[4];

    char* ws = (char*)d_ws;
    float2* P = (float2*)ws;
    size_t off = (size_t)NFIELD * NPIX * sizeof(float2);   // 42.47 MB
    float* psit = (float*)(ws + off);
    off += (size_t)NPIX * FPAD * sizeof(float);            // 12.58 MB
    float* Mout = (float*)(ws + off);
    size_t mout_bytes = (size_t)FPAD * NPAIR_PAD * 2 * sizeof(float);

    hipMemsetAsync(Mout, 0, mout_bytes, stream);

    k0_psit<<<dim3(NPIX / 64), dim3(256), 0, stream>>>(p2R, p2I, psit);
    k1_rowifft<<<dim3(64, NFIELD), dim3(256), 0, stream>>>(xhat, psiR, psiI, P);
    k2_colpass<<<dim3(16, NFIELD), dim3(256), 0, stream>>>(P);
    k3_rowfft<<<dim3(64, NFIELD), dim3(256), 0, stream>>>(P);
    c1_contract<<<dim3(KSPLIT2, 4), dim3(256), 0, stream>>>(P, psit, Mout);
    c2_assemble<<<dim3(81), dim3(256), 0, stream>>>(Mout, (float*)d_out);
}